// Round 3
// baseline (7917.704 us; speedup 1.0000x reference)
//
#include <hip/hip_runtime.h>
#include <hip/hip_bf16.h>
#include <math.h>

#define SEQP 1088
#define NBLK 17
#define DIM 768
#define NHEAD 12
#define HDIM 64
#define NLAYER 12
#define BATCH 2
#define ORIG 1025
#define NEGV -10000.0f

typedef __attribute__((ext_vector_type(8))) short short8;
typedef __attribute__((ext_vector_type(4))) float floatx4;
typedef unsigned short ushort_t;

__device__ __forceinline__ short f2bf(float f) {
    unsigned u = __float_as_uint(f);
    u += 0x7fff + ((u >> 16) & 1);   // RNE to bf16
    return (short)(u >> 16);
}
__device__ __forceinline__ float bf2f(ushort_t u) {
    return __uint_as_float(((unsigned)u) << 16);
}
// mode: 0 = harness float tensors are f32, 1 = bf16. Index is in ELEMENTS.
__device__ __forceinline__ float loadf(const void* p, size_t i, int mode) {
    return mode ? bf2f(((const ushort_t*)p)[i]) : ((const float*)p)[i];
}

// Detect input dtype from ln1_g (all ones): f32 -> first u32 = 0x3F800000,
// bf16 pair -> 0x3F803F80. Runs first every launch (ws re-poisoned).
__global__ void mode_kernel(const unsigned* __restrict__ ln1g, int* __restrict__ flag) {
    if (threadIdx.x == 0 && blockIdx.x == 0)
        flag[0] = (ln1g[0] == 0x3F803F80u) ? 1 : 0;
}

// ---------------------------------------------------------------------------
// GEMM: out[M,N] = A[M,K] @ W[woff + K,N] + bias[boff..] (+ epilogue).
// A is internal f32; W/bias dtype per mode; woff/boff are ELEMENT offsets.
// Split-bf16 (hi+lo, 3 MFMAs) => ~f32 accuracy on bf16 matrix cores.
// EPI: 0 none, 1 exact GELU, 2 residual add. Stores only (m%vmod)<vlim rows.
// ---------------------------------------------------------------------------
template<int EPI>
__global__ __launch_bounds__(256) void gemm_kernel(
    const float* __restrict__ A, int lda,
    const void* __restrict__ W, size_t woff, int ldw,
    const void* __restrict__ bias, size_t boff,
    const float* __restrict__ resid,
    float* __restrict__ out, int ldo,
    int M, int N, int K, int vmod, int vlim,
    const int* __restrict__ flagp)
{
    __shared__ __align__(16) short As[2][64][40];
    __shared__ __align__(16) short Bs[2][64][40];

    const int mode = flagp[0];
    const int t    = threadIdx.x;
    const int wave = t >> 6;
    const int lane = t & 63;
    const int lr   = lane & 15;
    const int quad = lane >> 4;
    const int m0   = blockIdx.y * 64;
    const int n0   = blockIdx.x * 64;

    floatx4 acc[4];
#pragma unroll
    for (int i = 0; i < 4; i++) acc[i] = (floatx4){0.f, 0.f, 0.f, 0.f};

    const int a_row = t >> 2;
    const int a_kg  = t & 3;
    const int a_sw  = (a_row >> 3) & 3;
    const int b_n   = t & 63;
    const int b_kg  = t >> 6;
    const int b_sw  = (b_n >> 3) & 3;
    const int fa_row = wave * 16 + lr;
    const int fa_sw  = (fa_row >> 3) & 3;

    for (int k0 = 0; k0 < K; k0 += 32) {
        {   // stage A tile (f32 -> bf16 hi+lo)
            int gm = m0 + a_row;
            floatx4 v0, v1;
            if (gm < M) {
                const float* p = A + (size_t)gm * lda + k0 + a_kg * 8;
                v0 = *(const floatx4*)p;
                v1 = *(const floatx4*)(p + 4);
            } else {
                v0 = (floatx4){0.f,0.f,0.f,0.f}; v1 = v0;
            }
            short8 hi, lo;
#pragma unroll
            for (int e = 0; e < 4; e++) {
                short h0 = f2bf(v0[e]); hi[e]   = h0; lo[e]   = f2bf(v0[e] - bf2f((ushort_t)h0));
                short h1 = f2bf(v1[e]); hi[e+4] = h1; lo[e+4] = f2bf(v1[e] - bf2f((ushort_t)h1));
            }
            int col = (a_kg ^ a_sw) * 8;
            *(short8*)&As[0][a_row][col] = hi;
            *(short8*)&As[1][a_row][col] = lo;
        }
        {   // stage B tile transposed (dtype per mode)
            short8 hi, lo;
            size_t off = woff + (size_t)(k0 + b_kg * 8) * ldw + n0 + b_n;
            if (mode) {
                const ushort_t* p = (const ushort_t*)W + off;
#pragma unroll
                for (int j = 0; j < 8; j++) { hi[j] = (short)p[(size_t)j * ldw]; lo[j] = 0; }
            } else {
                const float* p = (const float*)W + off;
#pragma unroll
                for (int j = 0; j < 8; j++) {
                    float v = p[(size_t)j * ldw];
                    short h = f2bf(v); hi[j] = h; lo[j] = f2bf(v - bf2f((ushort_t)h));
                }
            }
            int col = (b_kg ^ b_sw) * 8;
            *(short8*)&Bs[0][b_n][col] = hi;
            *(short8*)&Bs[1][b_n][col] = lo;
        }
        __syncthreads();
        int acol = (quad ^ fa_sw) * 8;
        short8 ah = *(const short8*)&As[0][fa_row][acol];
        short8 al = *(const short8*)&As[1][fa_row][acol];
#pragma unroll
        for (int nt = 0; nt < 4; nt++) {
            int n = nt * 16 + lr;
            int bcol = (quad ^ ((n >> 3) & 3)) * 8;
            short8 bh = *(const short8*)&Bs[0][n][bcol];
            short8 bl = *(const short8*)&Bs[1][n][bcol];
            acc[nt] = __builtin_amdgcn_mfma_f32_16x16x32_bf16(al, bh, acc[nt], 0, 0, 0);
            acc[nt] = __builtin_amdgcn_mfma_f32_16x16x32_bf16(ah, bl, acc[nt], 0, 0, 0);
            acc[nt] = __builtin_amdgcn_mfma_f32_16x16x32_bf16(ah, bh, acc[nt], 0, 0, 0);
        }
        __syncthreads();
    }

#pragma unroll
    for (int nt = 0; nt < 4; nt++) {
        int n = n0 + nt * 16 + lr;
        float bv = loadf(bias, boff + n, mode);
#pragma unroll
        for (int r = 0; r < 4; r++) {
            int m = m0 + wave * 16 + quad * 4 + r;
            if (m < M && (m % vmod) < vlim) {
                float v = acc[nt][r] + bv;
                if (EPI == 1) v = 0.5f * v * (1.0f + erff(v * 0.70710678118654752f));
                if (EPI == 2) v += resid[(size_t)m * ldo + n];
                out[(size_t)m * ldo + n] = v;
            }
        }
    }
}

// ---------------------------------------------------------------------------
// LayerNorm over D=768 (f32 in/out). gamma/beta dtype per mode, element offset.
// Pad rows (s>=ORIG) zeroed.
// ---------------------------------------------------------------------------
__global__ __launch_bounds__(256) void ln_kernel(
    const float* __restrict__ X, const void* __restrict__ g,
    const void* __restrict__ bta, size_t goff, float* __restrict__ out,
    const int* __restrict__ flagp)
{
    const int mode = flagp[0];
    int r = blockIdx.x;
    int s = r % SEQP;
    int t = threadIdx.x;
    float* o = out + (size_t)r * DIM;
    if (s >= ORIG) {
        o[t] = 0.f; o[t + 256] = 0.f; o[t + 512] = 0.f;
        return;
    }
    const float* x = X + (size_t)r * DIM;
    float v0 = x[t], v1 = x[t + 256], v2 = x[t + 512];
    float sum = v0 + v1 + v2;
    float sq  = v0 * v0 + v1 * v1 + v2 * v2;
    for (int off = 32; off >= 1; off >>= 1) {
        sum += __shfl_down(sum, off);
        sq  += __shfl_down(sq, off);
    }
    __shared__ float ws_[4], wq_[4], stats[2];
    int wv = t >> 6, ln = t & 63;
    if (ln == 0) { ws_[wv] = sum; wq_[wv] = sq; }
    __syncthreads();
    if (t == 0) {
        float S = ws_[0] + ws_[1] + ws_[2] + ws_[3];
        float Q = wq_[0] + wq_[1] + wq_[2] + wq_[3];
        float mean = S * (1.0f / DIM);
        float var  = Q * (1.0f / DIM) - mean * mean;
        stats[0] = mean; stats[1] = rsqrtf(var + 1e-5f);
    }
    __syncthreads();
    float mean = stats[0], rstd = stats[1];
    o[t]       = (v0 - mean) * rstd * loadf(g, goff + t, mode)       + loadf(bta, goff + t, mode);
    o[t + 256] = (v1 - mean) * rstd * loadf(g, goff + t + 256, mode) + loadf(bta, goff + t + 256, mode);
    o[t + 512] = (v2 - mean) * rstd * loadf(g, goff + t + 512, mode) + loadf(bta, goff + t + 512, mode);
}

// Final LN -> output (dtype per mode), compact (B, ORIG, D)
__global__ __launch_bounds__(256) void ln_out_kernel(
    const float* __restrict__ X, const void* __restrict__ g,
    const void* __restrict__ bta, void* __restrict__ out,
    const int* __restrict__ flagp)
{
    const int mode = flagp[0];
    int r = blockIdx.x;
    int b = r / SEQP, s = r % SEQP;
    if (s >= ORIG) return;
    int t = threadIdx.x;
    const float* x = X + (size_t)r * DIM;
    float v0 = x[t], v1 = x[t + 256], v2 = x[t + 512];
    float sum = v0 + v1 + v2;
    float sq  = v0 * v0 + v1 * v1 + v2 * v2;
    for (int off = 32; off >= 1; off >>= 1) {
        sum += __shfl_down(sum, off);
        sq  += __shfl_down(sq, off);
    }
    __shared__ float ws_[4], wq_[4], stats[2];
    int wv = t >> 6, ln = t & 63;
    if (ln == 0) { ws_[wv] = sum; wq_[wv] = sq; }
    __syncthreads();
    if (t == 0) {
        float S = ws_[0] + ws_[1] + ws_[2] + ws_[3];
        float Q = wq_[0] + wq_[1] + wq_[2] + wq_[3];
        float mean = S * (1.0f / DIM);
        float var  = Q * (1.0f / DIM) - mean * mean;
        stats[0] = mean; stats[1] = rsqrtf(var + 1e-5f);
    }
    __syncthreads();
    float mean = stats[0], rstd = stats[1];
    size_t base = ((size_t)b * ORIG + s) * DIM;
    float r0 = (v0 - mean) * rstd * loadf(g, t, mode)       + loadf(bta, t, mode);
    float r1 = (v1 - mean) * rstd * loadf(g, t + 256, mode) + loadf(bta, t + 256, mode);
    float r2 = (v2 - mean) * rstd * loadf(g, t + 512, mode) + loadf(bta, t + 512, mode);
    if (mode) {
        ushort_t* o = (ushort_t*)out + base;
        o[t] = (ushort_t)f2bf(r0); o[t + 256] = (ushort_t)f2bf(r1); o[t + 512] = (ushort_t)f2bf(r2);
    } else {
        float* o = (float*)out + base;
        o[t] = r0; o[t + 256] = r1; o[t + 512] = r2;
    }
}

// ---------------------------------------------------------------------------
// BigBird block-sparse attention (unchanged from r2 analysis; all f32).
// ---------------------------------------------------------------------------
__global__ __launch_bounds__(256) void attn_kernel(
    const float* __restrict__ qm, const float* __restrict__ km,
    const float* __restrict__ vm, const int* __restrict__ rand_attn,
    float* __restrict__ ctx)
{
    __shared__ float Qs[64][67];
    __shared__ float Ks[32][67];
    __shared__ float Vs[32][67];
    __shared__ float Ss[64][35];
    __shared__ float mrow[64], lrow[64], arow[64];

    int blk = blockIdx.x;
    int qi = blk % NBLK;
    int h  = (blk / NBLK) % NHEAD;
    int b  = blk / (NBLK * NHEAD);
    int t  = threadIdx.x;

    int list[NBLK];
    int nk;
    if (qi == 0 || qi == NBLK - 1) {
        nk = NBLK;
        for (int i = 0; i < NBLK; i++) list[i] = i;
    } else {
        const int* ra = rand_attn + (h * (NBLK - 2) + (qi - 1)) * 3;
        if (qi == 1)           { list[0]=0; list[1]=1;    list[2]=2;  list[3]=16; nk=4; }
        else if (qi == NBLK-2) { list[0]=0; list[1]=14;   list[2]=15; list[3]=16; nk=4; }
        else { list[0]=0; list[1]=qi-1; list[2]=qi; list[3]=qi+1; list[4]=16; nk=5; }
        list[nk++] = ra[0]; list[nk++] = ra[1]; list[nk++] = ra[2];
    }

    {
        int row = t >> 2, c0 = (t & 3) * 16;
        const float* p = qm + ((size_t)(b * SEQP + qi * 64 + row)) * DIM + h * HDIM + c0;
#pragma unroll
        for (int j = 0; j < 16; j++) Qs[row][c0 + j] = p[j] * 0.125f;
    }
    if (t < 64) { mrow[t] = -1e30f; lrow[t] = 0.f; }

    float O[4][4];
#pragma unroll
    for (int i = 0; i < 4; i++)
#pragma unroll
        for (int j = 0; j < 4; j++) O[i][j] = 0.f;

    const int q0 = (t >> 4) * 4;
    const int x0 = (t & 15);

    for (int ib = 0; ib < nk; ib++) {
        int kb = list[ib];
        for (int half = 0; half < 2; half++) {
            __syncthreads();
            {
                int row = t >> 3, c0 = (t & 7) * 8;
                size_t base = ((size_t)(b * SEQP + kb * 64 + half * 32 + row)) * DIM + h * HDIM + c0;
#pragma unroll
                for (int j = 0; j < 8; j++) Ks[row][c0 + j] = km[base + j];
#pragma unroll
                for (int j = 0; j < 8; j++) Vs[row][c0 + j] = vm[base + j];
            }
            __syncthreads();
            {
                float s2[4][2];
#pragma unroll
                for (int i = 0; i < 4; i++) { s2[i][0] = 0.f; s2[i][1] = 0.f; }
                int kc0 = x0 * 2;
                for (int kk = 0; kk < 64; kk++) {
                    float k0v = Ks[kc0][kk], k1v = Ks[kc0 + 1][kk];
#pragma unroll
                    for (int i = 0; i < 4; i++) {
                        float qv = Qs[q0 + i][kk];
                        s2[i][0] += qv * k0v;
                        s2[i][1] += qv * k1v;
                    }
                }
                bool m16 = (kb == 16);
                float add0 = (m16 && (half * 32 + kc0)     >= 1) ? NEGV : 0.f;
                float add1 = (m16 && (half * 32 + kc0 + 1) >= 1) ? NEGV : 0.f;
#pragma unroll
                for (int i = 0; i < 4; i++) {
                    Ss[q0 + i][kc0]     = s2[i][0] + add0;
                    Ss[q0 + i][kc0 + 1] = s2[i][1] + add1;
                }
            }
            __syncthreads();
            if (t < 64) {
                float mold = mrow[t];
                float bm = -1e30f;
                for (int j = 0; j < 32; j++) bm = fmaxf(bm, Ss[t][j]);
                float mnew = fmaxf(mold, bm);
                float al = __expf(mold - mnew);
                float rs = 0.f;
                for (int j = 0; j < 32; j++) {
                    float pv = __expf(Ss[t][j] - mnew);
                    Ss[t][j] = pv;
                    rs += pv;
                }
                lrow[t] = lrow[t] * al + rs;
                mrow[t] = mnew;
                arow[t] = al;
            }
            __syncthreads();
            {
                int d0 = x0 * 4;
                float al[4];
#pragma unroll
                for (int i = 0; i < 4; i++) {
                    al[i] = arow[q0 + i];
                    O[i][0] *= al[i]; O[i][1] *= al[i]; O[i][2] *= al[i]; O[i][3] *= al[i];
                }
                for (int kk = 0; kk < 32; kk++) {
                    float v0 = Vs[kk][d0], v1 = Vs[kk][d0 + 1];
                    float v2 = Vs[kk][d0 + 2], v3 = Vs[kk][d0 + 3];
#pragma unroll
                    for (int i = 0; i < 4; i++) {
                        float pv = Ss[q0 + i][kk];
                        O[i][0] += pv * v0; O[i][1] += pv * v1;
                        O[i][2] += pv * v2; O[i][3] += pv * v3;
                    }
                }
            }
        }
    }
    {
        int d0 = x0 * 4;
#pragma unroll
        for (int i = 0; i < 4; i++) {
            float inv = 1.0f / lrow[q0 + i];
            float* o = ctx + ((size_t)(b * SEQP + qi * 64 + q0 + i)) * DIM + h * HDIM + d0;
            o[0] = O[i][0] * inv; o[1] = O[i][1] * inv;
            o[2] = O[i][2] * inv; o[3] = O[i][3] * inv;
        }
    }
}

__global__ __launch_bounds__(256) void patch_kernel(
    const void* __restrict__ px, float* __restrict__ patches,
    const int* __restrict__ flagp)
{
    const int mode = flagp[0];
    int idx = blockIdx.x * 256 + threadIdx.x;
    int f = idx % 768;
    int rest = idx / 768;
    int p = rest % 1024;
    int b = rest / 1024;
    int gy = p >> 5, gx = p & 31;
    int c = f >> 8, rr = f & 255;
    int py = rr >> 4, pxl = rr & 15;
    patches[idx] = loadf(px, (((size_t)(b * 3 + c) * 512) + gy * 16 + py) * 512 + gx * 16 + pxl, mode);
}

__global__ __launch_bounds__(256) void assemble_kernel(
    const float* __restrict__ pe, const void* __restrict__ cls,
    const void* __restrict__ pos, float* __restrict__ X,
    const int* __restrict__ flagp)
{
    const int mode = flagp[0];
    int idx = blockIdx.x * 256 + threadIdx.x;
    int d = idx % 768;
    int rest = idx / 768;
    int s = rest % SEQP;
    int b = rest / SEQP;
    float v;
    if (s == 0)          v = loadf(cls, d, mode) + loadf(pos, d, mode);
    else if (s < ORIG)   v = pe[((size_t)(b * 1024 + s - 1)) * 768 + d] + loadf(pos, (size_t)s * 768 + d, mode);
    else                 v = 0.f;
    X[idx] = v;
}

extern "C" void kernel_launch(void* const* d_in, const int* in_sizes, int n_in,
                              void* d_out, int out_size, void* d_ws, size_t ws_size,
                              hipStream_t stream)
{
    const void* pixel   = d_in[0];
    const void* patch_w = d_in[1];
    const void* patch_b = d_in[2];
    const void* cls     = d_in[3];
    const void* pos     = d_in[4];
    const void* Wq  = d_in[5];
    const void* bq  = d_in[6];
    const void* Wk  = d_in[7];
    const void* bk  = d_in[8];
    const void* Wv  = d_in[9];
    const void* bv  = d_in[10];
    const void* Wo  = d_in[11];
    const void* bo  = d_in[12];
    const void* ln1g = d_in[13];
    const void* ln1b = d_in[14];
    const void* ln2g = d_in[15];
    const void* ln2b = d_in[16];
    const void* fw1 = d_in[17];
    const void* fb1 = d_in[18];
    const void* fw2 = d_in[19];
    const void* fb2 = d_in[20];
    const void* ng  = d_in[21];
    const void* nb  = d_in[22];
    const int*  ra  = (const int*)d_in[23];

    float* ws = (float*)d_ws;
    const size_t SZ = (size_t)BATCH * SEQP * DIM;   // 1,671,168 floats
    float* X    = ws;
    float* XN   = ws + SZ;
    float* QB   = ws + 2 * SZ;
    float* KB   = ws + 3 * SZ;
    float* VB   = ws + 4 * SZ;
    float* CTX  = ws + 5 * SZ;
    float* FFH  = ws + 2 * SZ;        // aliases QB..CTX (exactly 4*SZ), dead then
    float* PATCH = ws + SZ;           // aliases XN (pre-layer only)
    float* POUT  = ws + 2 * SZ;       // aliases QB (pre-layer only)
    int*   flag  = (int*)(ws + 6 * SZ);

    const int BIG = 1 << 30;
    dim3 blk(256);

    mode_kernel<<<dim3(1), dim3(64), 0, stream>>>((const unsigned*)ln1g, flag);

    patch_kernel<<<dim3((BATCH * 1024 * 768) / 256), blk, 0, stream>>>(pixel, PATCH, flag);
    gemm_kernel<0><<<dim3(12, 32), blk, 0, stream>>>(PATCH, 768, patch_w, 0, 768, patch_b, 0,
                                                     nullptr, POUT, 768, 2048, 768, 768, BIG, BIG, flag);
    assemble_kernel<<<dim3((BATCH * SEQP * 768) / 256), blk, 0, stream>>>(POUT, cls, pos, X, flag);

    for (int i = 0; i < NLAYER; i++) {
        const size_t woE = (size_t)i * 768 * 768;     // element offsets
        const size_t bE  = (size_t)i * 768;
        const size_t w1E = (size_t)i * 768 * 3072;
        const size_t b1E = (size_t)i * 3072;
        ln_kernel<<<dim3(BATCH * SEQP), blk, 0, stream>>>(X, ln1g, ln1b, bE, XN, flag);
        gemm_kernel<0><<<dim3(12, 34), blk, 0, stream>>>(XN, 768, Wq, woE, 768, bq, bE,
                                                         nullptr, QB, 768, BATCH * SEQP, 768, 768, BIG, BIG, flag);
        gemm_kernel<0><<<dim3(12, 34), blk, 0, stream>>>(XN, 768, Wk, woE, 768, bk, bE,
                                                         nullptr, KB, 768, BATCH * SEQP, 768, 768, BIG, BIG, flag);
        gemm_kernel<0><<<dim3(12, 34), blk, 0, stream>>>(XN, 768, Wv, woE, 768, bv, bE,
                                                         nullptr, VB, 768, BATCH * SEQP, 768, 768, BIG, BIG, flag);
        attn_kernel<<<dim3(BATCH * NHEAD * NBLK), blk, 0, stream>>>(QB, KB, VB, ra, CTX);
        gemm_kernel<2><<<dim3(12, 34), blk, 0, stream>>>(CTX, 768, Wo, woE, 768, bo, bE,
                                                         X, X, 768, BATCH * SEQP, 768, 768, SEQP, ORIG, flag);
        ln_kernel<<<dim3(BATCH * SEQP), blk, 0, stream>>>(X, ln2g, ln2b, bE, XN, flag);
        gemm_kernel<1><<<dim3(48, 34), blk, 0, stream>>>(XN, 768, fw1, w1E, 3072, fb1, b1E,
                                                         nullptr, FFH, 3072, BATCH * SEQP, 3072, 768, BIG, BIG, flag);
        gemm_kernel<2><<<dim3(12, 34), blk, 0, stream>>>(FFH, 3072, fw2, w1E, 768, fb2, b1E,
                                                         X, X, 768, BATCH * SEQP, 768, 3072, SEQP, ORIG, flag);
    }
    ln_out_kernel<<<dim3(BATCH * SEQP), blk, 0, stream>>>(X, ng, nb, d_out, flag);
}

// Round 4
// 5734.351 us; speedup vs baseline: 1.3807x; 1.3807x over previous
//
#include <hip/hip_runtime.h>
#include <hip/hip_bf16.h>
#include <math.h>

#define SEQP 1088
#define NBLK 17
#define DIM 768
#define NHEAD 12
#define HDIM 64
#define NLAYER 12
#define BATCH 2
#define ORIG 1025
#define NEGV -10000.0f

typedef __attribute__((ext_vector_type(8))) short short8;
typedef __attribute__((ext_vector_type(4))) float floatx4;
typedef unsigned short ushort_t;

__device__ __forceinline__ short f2bf(float f) {
    unsigned u = __float_as_uint(f);
    u += 0x7fff + ((u >> 16) & 1);   // RNE to bf16
    return (short)(u >> 16);
}
__device__ __forceinline__ float bf2f(ushort_t u) {
    return __uint_as_float(((unsigned)u) << 16);
}
// mode: 0 = harness float tensors are f32, 1 = bf16. Index is in ELEMENTS.
__device__ __forceinline__ float loadf(const void* p, size_t i, int mode) {
    return mode ? bf2f(((const ushort_t*)p)[i]) : ((const float*)p)[i];
}

// Detect input dtype from ln1_g (all ones): f32 -> 0x3F800000, bf16 pair ->
// 0x3F803F80. Runs first every launch (ws re-poisoned each call).
__global__ void mode_kernel(const unsigned* __restrict__ ln1g, int* __restrict__ flag) {
    if (threadIdx.x == 0 && blockIdx.x == 0)
        flag[0] = (ln1g[0] == 0x3F803F80u) ? 1 : 0;
}

// ---------------------------------------------------------------------------
// GEMM: out[M,N] = A[M,K] @ W[woff + K,N] + bias[boff..] (+ epilogue).
// A internal f32; W/bias dtype per mode. Split-bf16 (hi+lo, 3 MFMAs).
// EPI: 0 none, 1 exact GELU, 2 residual add. OBF: 1 => bf16 output.
// Stores only rows with (m % vmod) < vlim.
// ---------------------------------------------------------------------------
template<int EPI, int OBF>
__global__ __launch_bounds__(256) void gemm_kernel(
    const float* __restrict__ A, int lda,
    const void* __restrict__ W, size_t woff, int ldw,
    const void* __restrict__ bias, size_t boff,
    const float* __restrict__ resid,
    void* __restrict__ out, int ldo,
    int M, int N, int K, int vmod, int vlim,
    const int* __restrict__ flagp)
{
    __shared__ __align__(16) short As[2][64][40];
    __shared__ __align__(16) short Bs[2][64][40];

    const int mode = flagp[0];
    const int t    = threadIdx.x;
    const int wave = t >> 6;
    const int lane = t & 63;
    const int lr   = lane & 15;
    const int quad = lane >> 4;
    const int m0   = blockIdx.y * 64;
    const int n0   = blockIdx.x * 64;

    floatx4 acc[4];
#pragma unroll
    for (int i = 0; i < 4; i++) acc[i] = (floatx4){0.f, 0.f, 0.f, 0.f};

    const int a_row = t >> 2;
    const int a_kg  = t & 3;
    const int a_sw  = (a_row >> 3) & 3;
    const int b_n   = t & 63;
    const int b_kg  = t >> 6;
    const int b_sw  = (b_n >> 3) & 3;
    const int fa_row = wave * 16 + lr;
    const int fa_sw  = (fa_row >> 3) & 3;

    for (int k0 = 0; k0 < K; k0 += 32) {
        {   // stage A tile (f32 -> bf16 hi+lo)
            int gm = m0 + a_row;
            floatx4 v0, v1;
            if (gm < M) {
                const float* p = A + (size_t)gm * lda + k0 + a_kg * 8;
                v0 = *(const floatx4*)p;
                v1 = *(const floatx4*)(p + 4);
            } else {
                v0 = (floatx4){0.f,0.f,0.f,0.f}; v1 = v0;
            }
            short8 hi, lo;
#pragma unroll
            for (int e = 0; e < 4; e++) {
                short h0 = f2bf(v0[e]); hi[e]   = h0; lo[e]   = f2bf(v0[e] - bf2f((ushort_t)h0));
                short h1 = f2bf(v1[e]); hi[e+4] = h1; lo[e+4] = f2bf(v1[e] - bf2f((ushort_t)h1));
            }
            int col = (a_kg ^ a_sw) * 8;
            *(short8*)&As[0][a_row][col] = hi;
            *(short8*)&As[1][a_row][col] = lo;
        }
        {   // stage B tile transposed (dtype per mode)
            short8 hi, lo;
            size_t off = woff + (size_t)(k0 + b_kg * 8) * ldw + n0 + b_n;
            if (mode) {
                const ushort_t* p = (const ushort_t*)W + off;
#pragma unroll
                for (int j = 0; j < 8; j++) { hi[j] = (short)p[(size_t)j * ldw]; lo[j] = 0; }
            } else {
                const float* p = (const float*)W + off;
#pragma unroll
                for (int j = 0; j < 8; j++) {
                    float v = p[(size_t)j * ldw];
                    short h = f2bf(v); hi[j] = h; lo[j] = f2bf(v - bf2f((ushort_t)h));
                }
            }
            int col = (b_kg ^ b_sw) * 8;
            *(short8*)&Bs[0][b_n][col] = hi;
            *(short8*)&Bs[1][b_n][col] = lo;
        }
        __syncthreads();
        int acol = (quad ^ fa_sw) * 8;
        short8 ah = *(const short8*)&As[0][fa_row][acol];
        short8 al = *(const short8*)&As[1][fa_row][acol];
#pragma unroll
        for (int nt = 0; nt < 4; nt++) {
            int n = nt * 16 + lr;
            int bcol = (quad ^ ((n >> 3) & 3)) * 8;
            short8 bh = *(const short8*)&Bs[0][n][bcol];
            short8 bl = *(const short8*)&Bs[1][n][bcol];
            acc[nt] = __builtin_amdgcn_mfma_f32_16x16x32_bf16(al, bh, acc[nt], 0, 0, 0);
            acc[nt] = __builtin_amdgcn_mfma_f32_16x16x32_bf16(ah, bl, acc[nt], 0, 0, 0);
            acc[nt] = __builtin_amdgcn_mfma_f32_16x16x32_bf16(ah, bh, acc[nt], 0, 0, 0);
        }
        __syncthreads();
    }

#pragma unroll
    for (int nt = 0; nt < 4; nt++) {
        int n = n0 + nt * 16 + lr;
        float bv = loadf(bias, boff + n, mode);
#pragma unroll
        for (int r = 0; r < 4; r++) {
            int m = m0 + wave * 16 + quad * 4 + r;
            if (m < M && (m % vmod) < vlim) {
                float v = acc[nt][r] + bv;
                if (EPI == 1) v = 0.5f * v * (1.0f + erff(v * 0.70710678118654752f));
                if (EPI == 2) v += resid[(size_t)m * ldo + n];
                if (OBF) ((ushort_t*)out)[(size_t)m * ldo + n] = (ushort_t)f2bf(v);
                else     ((float*)out)[(size_t)m * ldo + n] = v;
            }
        }
    }
}

// ---------------------------------------------------------------------------
// LayerNorm over D=768 (f32 in/out). gamma/beta dtype per mode, element off.
// Pad rows (s>=ORIG) zeroed.
// ---------------------------------------------------------------------------
__global__ __launch_bounds__(256) void ln_kernel(
    const float* __restrict__ X, const void* __restrict__ g,
    const void* __restrict__ bta, size_t goff, float* __restrict__ out,
    const int* __restrict__ flagp)
{
    const int mode = flagp[0];
    int r = blockIdx.x;
    int s = r % SEQP;
    int t = threadIdx.x;
    float* o = out + (size_t)r * DIM;
    if (s >= ORIG) {
        o[t] = 0.f; o[t + 256] = 0.f; o[t + 512] = 0.f;
        return;
    }
    const float* x = X + (size_t)r * DIM;
    float v0 = x[t], v1 = x[t + 256], v2 = x[t + 512];
    float sum = v0 + v1 + v2;
    float sq  = v0 * v0 + v1 * v1 + v2 * v2;
    for (int off = 32; off >= 1; off >>= 1) {
        sum += __shfl_down(sum, off);
        sq  += __shfl_down(sq, off);
    }
    __shared__ float ws_[4], wq_[4], stats[2];
    int wv = t >> 6, ln = t & 63;
    if (ln == 0) { ws_[wv] = sum; wq_[wv] = sq; }
    __syncthreads();
    if (t == 0) {
        float S = ws_[0] + ws_[1] + ws_[2] + ws_[3];
        float Q = wq_[0] + wq_[1] + wq_[2] + wq_[3];
        float mean = S * (1.0f / DIM);
        float var  = Q * (1.0f / DIM) - mean * mean;
        stats[0] = mean; stats[1] = rsqrtf(var + 1e-5f);
    }
    __syncthreads();
    float mean = stats[0], rstd = stats[1];
    o[t]       = (v0 - mean) * rstd * loadf(g, goff + t, mode)       + loadf(bta, goff + t, mode);
    o[t + 256] = (v1 - mean) * rstd * loadf(g, goff + t + 256, mode) + loadf(bta, goff + t + 256, mode);
    o[t + 512] = (v2 - mean) * rstd * loadf(g, goff + t + 512, mode) + loadf(bta, goff + t + 512, mode);
}

// Final LN -> output (dtype per mode), compact (B, ORIG, D)
__global__ __launch_bounds__(256) void ln_out_kernel(
    const float* __restrict__ X, const void* __restrict__ g,
    const void* __restrict__ bta, void* __restrict__ out,
    const int* __restrict__ flagp)
{
    const int mode = flagp[0];
    int r = blockIdx.x;
    int b = r / SEQP, s = r % SEQP;
    if (s >= ORIG) return;
    int t = threadIdx.x;
    const float* x = X + (size_t)r * DIM;
    float v0 = x[t], v1 = x[t + 256], v2 = x[t + 512];
    float sum = v0 + v1 + v2;
    float sq  = v0 * v0 + v1 * v1 + v2 * v2;
    for (int off = 32; off >= 1; off >>= 1) {
        sum += __shfl_down(sum, off);
        sq  += __shfl_down(sq, off);
    }
    __shared__ float ws_[4], wq_[4], stats[2];
    int wv = t >> 6, ln = t & 63;
    if (ln == 0) { ws_[wv] = sum; wq_[wv] = sq; }
    __syncthreads();
    if (t == 0) {
        float S = ws_[0] + ws_[1] + ws_[2] + ws_[3];
        float Q = wq_[0] + wq_[1] + wq_[2] + wq_[3];
        float mean = S * (1.0f / DIM);
        float var  = Q * (1.0f / DIM) - mean * mean;
        stats[0] = mean; stats[1] = rsqrtf(var + 1e-5f);
    }
    __syncthreads();
    float mean = stats[0], rstd = stats[1];
    size_t base = ((size_t)b * ORIG + s) * DIM;
    float r0 = (v0 - mean) * rstd * loadf(g, t, mode)       + loadf(bta, t, mode);
    float r1 = (v1 - mean) * rstd * loadf(g, t + 256, mode) + loadf(bta, t + 256, mode);
    float r2 = (v2 - mean) * rstd * loadf(g, t + 512, mode) + loadf(bta, t + 512, mode);
    if (mode) {
        ushort_t* o = (ushort_t*)out + base;
        o[t] = (ushort_t)f2bf(r0); o[t + 256] = (ushort_t)f2bf(r1); o[t + 512] = (ushort_t)f2bf(r2);
    } else {
        float* o = (float*)out + base;
        o[t] = r0; o[t + 256] = r1; o[t + 512] = r2;
    }
}

// ---------------------------------------------------------------------------
// BigBird block-sparse attention, MFMA version. One block per (qi, h, b);
// 4 waves; wave w owns Q-strip rows [16w,16w+16). Q in registers (A-frags).
// Per k-block: K -> LDS [k][d], V -> LDS transposed [d][k] (both bf16),
// S = Q K^T via 16x16x32 MFMA, in-wave online softmax (shfl over the 16-lane
// C/D col group), P -> per-wave LDS (C/D -> A layout), O += P V via MFMA.
// Only mask: key pos >= ORIG. Key-block list is the ref's literal multiset.
// ---------------------------------------------------------------------------
__global__ __launch_bounds__(256) void attn_kernel(
    const ushort_t* __restrict__ qm, const ushort_t* __restrict__ km,
    const ushort_t* __restrict__ vm, const int* __restrict__ rand_attn,
    float* __restrict__ ctx)
{
    __shared__ __align__(16) ushort_t Ks[64][72];     // [krow][d]
    __shared__ __align__(16) ushort_t VT[64][72];     // [d][vrow]
    __shared__ __align__(16) ushort_t Ps[4][16][72];  // per-wave P [q][k]

    const int qi = blockIdx.x;
    const int h  = blockIdx.y;
    const int b  = blockIdx.z;
    const int t  = threadIdx.x;
    const int w    = t >> 6;
    const int lane = t & 63;
    const int lr   = lane & 15;
    const int quad = lane >> 4;

    int list[NBLK];
    int nk;
    if (qi == 0 || qi == NBLK - 1) {
        nk = NBLK;
        for (int i = 0; i < NBLK; i++) list[i] = i;
    } else {
        const int* ra = rand_attn + (h * (NBLK - 2) + (qi - 1)) * 3;
        if (qi == 1)           { list[0]=0; list[1]=1;  list[2]=2;  list[3]=16; nk=4; }
        else if (qi == NBLK-2) { list[0]=0; list[1]=14; list[2]=15; list[3]=16; nk=4; }
        else { list[0]=0; list[1]=qi-1; list[2]=qi; list[3]=qi+1; list[4]=16; nk=5; }
        list[nk++] = ra[0]; list[nk++] = ra[1]; list[nk++] = ra[2];
    }

    // Q strip A-fragments (rows 16w + lr, d = quad*8+j and +32)
    const ushort_t* qp = qm + ((size_t)(b * SEQP + qi * 64 + w * 16 + lr)) * DIM + h * HDIM + quad * 8;
    short8 aq0 = *(const short8*)qp;
    short8 aq1 = *(const short8*)(qp + 32);

    floatx4 O[4];
#pragma unroll
    for (int i = 0; i < 4; i++) O[i] = (floatx4){0.f, 0.f, 0.f, 0.f};
    float m_[4], l_[4];
#pragma unroll
    for (int r = 0; r < 4; r++) { m_[r] = -1e30f; l_[r] = 0.f; }

    // staging index precompute
    const int k_row = t >> 2, k_dg = (t & 3) * 16;
    const int v_d   = t & 63, v_r0 = (t >> 6) * 16;

    for (int ib = 0; ib < nk; ib++) {
        const int kb = list[ib];
        __syncthreads();   // previous tiles consumed
        {   // stage K [krow][d]
            const ushort_t* kp = km + ((size_t)(b * SEQP + kb * 64 + k_row)) * DIM + h * HDIM + k_dg;
            *(short8*)&Ks[k_row][k_dg]     = *(const short8*)kp;
            *(short8*)&Ks[k_row][k_dg + 8] = *(const short8*)(kp + 8);
        }
        {   // stage V transposed [d][vrow], paired u32 writes
            const ushort_t* vp = vm + ((size_t)(b * SEQP + kb * 64 + v_r0)) * DIM + h * HDIM + v_d;
            ushort_t tmp[16];
#pragma unroll
            for (int r = 0; r < 16; r++) tmp[r] = vp[(size_t)r * DIM];
#pragma unroll
            for (int i = 0; i < 8; i++) {
                unsigned pk = (unsigned)tmp[2 * i] | ((unsigned)tmp[2 * i + 1] << 16);
                *(unsigned*)&VT[v_d][v_r0 + 2 * i] = pk;
            }
        }
        __syncthreads();

        // S = Q K^T : 4 col-tiles of 16 k's
        float s[4][4];
#pragma unroll
        for (int kt = 0; kt < 4; kt++) {
            short8 b0 = *(const short8*)&Ks[kt * 16 + lr][quad * 8];
            short8 b1 = *(const short8*)&Ks[kt * 16 + lr][32 + quad * 8];
            floatx4 z = (floatx4){0.f, 0.f, 0.f, 0.f};
            z = __builtin_amdgcn_mfma_f32_16x16x32_bf16(aq0, b0, z, 0, 0, 0);
            z = __builtin_amdgcn_mfma_f32_16x16x32_bf16(aq1, b1, z, 0, 0, 0);
            float madd = (kb * 64 + kt * 16 + lr >= ORIG) ? NEGV : 0.f;
#pragma unroll
            for (int r = 0; r < 4; r++) s[kt][r] = z[r] * 0.125f + madd;
        }
        // in-wave online softmax (rows = quad*4+r, cols across 16 lanes)
        float rmax[4];
#pragma unroll
        for (int r = 0; r < 4; r++)
            rmax[r] = fmaxf(fmaxf(s[0][r], s[1][r]), fmaxf(s[2][r], s[3][r]));
#pragma unroll
        for (int d = 1; d < 16; d <<= 1)
#pragma unroll
            for (int r = 0; r < 4; r++) rmax[r] = fmaxf(rmax[r], __shfl_xor(rmax[r], d));
        float alpha[4];
#pragma unroll
        for (int r = 0; r < 4; r++) {
            float mnew = fmaxf(m_[r], rmax[r]);
            alpha[r] = __expf(m_[r] - mnew);
            m_[r] = mnew;
        }
        float rsum[4];
#pragma unroll
        for (int r = 0; r < 4; r++) rsum[r] = 0.f;
#pragma unroll
        for (int kt = 0; kt < 4; kt++)
#pragma unroll
            for (int r = 0; r < 4; r++) {
                float pv = __expf(s[kt][r] - m_[r]);
                s[kt][r] = pv;
                rsum[r] += pv;
            }
#pragma unroll
        for (int d = 1; d < 16; d <<= 1)
#pragma unroll
            for (int r = 0; r < 4; r++) rsum[r] += __shfl_xor(rsum[r], d);
#pragma unroll
        for (int r = 0; r < 4; r++) l_[r] = l_[r] * alpha[r] + rsum[r];

        // P -> LDS (C/D layout -> [q][k]), then rescale O
#pragma unroll
        for (int kt = 0; kt < 4; kt++)
#pragma unroll
            for (int r = 0; r < 4; r++)
                Ps[w][quad * 4 + r][kt * 16 + lr] = (ushort_t)f2bf(s[kt][r]);
#pragma unroll
        for (int nt = 0; nt < 4; nt++)
#pragma unroll
            for (int r = 0; r < 4; r++) O[nt][r] *= alpha[r];

        // O += P V
        short8 pa0 = *(const short8*)&Ps[w][lr][quad * 8];
        short8 pa1 = *(const short8*)&Ps[w][lr][32 + quad * 8];
#pragma unroll
        for (int nt = 0; nt < 4; nt++) {
            short8 v0 = *(const short8*)&VT[nt * 16 + lr][quad * 8];
            short8 v1 = *(const short8*)&VT[nt * 16 + lr][32 + quad * 8];
            O[nt] = __builtin_amdgcn_mfma_f32_16x16x32_bf16(pa0, v0, O[nt], 0, 0, 0);
            O[nt] = __builtin_amdgcn_mfma_f32_16x16x32_bf16(pa1, v1, O[nt], 0, 0, 0);
        }
    }

    // write ctx rows (C/D layout: row = quad*4+r, col = nt*16+lr)
#pragma unroll
    for (int r = 0; r < 4; r++) {
        float inv = 1.0f / l_[r];
        float* op = ctx + ((size_t)(b * SEQP + qi * 64 + w * 16 + quad * 4 + r)) * DIM + h * HDIM + lr;
#pragma unroll
        for (int nt = 0; nt < 4; nt++) op[nt * 16] = O[nt][r] * inv;
    }
}

__global__ __launch_bounds__(256) void patch_kernel(
    const void* __restrict__ px, float* __restrict__ patches,
    const int* __restrict__ flagp)
{
    const int mode = flagp[0];
    int idx = blockIdx.x * 256 + threadIdx.x;
    int f = idx % 768;
    int rest = idx / 768;
    int p = rest % 1024;
    int b = rest / 1024;
    int gy = p >> 5, gx = p & 31;
    int c = f >> 8, rr = f & 255;
    int py = rr >> 4, pxl = rr & 15;
    patches[idx] = loadf(px, (((size_t)(b * 3 + c) * 512) + gy * 16 + py) * 512 + gx * 16 + pxl, mode);
}

__global__ __launch_bounds__(256) void assemble_kernel(
    const float* __restrict__ pe, const void* __restrict__ cls,
    const void* __restrict__ pos, float* __restrict__ X,
    const int* __restrict__ flagp)
{
    const int mode = flagp[0];
    int idx = blockIdx.x * 256 + threadIdx.x;
    int d = idx % 768;
    int rest = idx / 768;
    int s = rest % SEQP;
    int b = rest / SEQP;
    float v;
    if (s == 0)          v = loadf(cls, d, mode) + loadf(pos, d, mode);
    else if (s < ORIG)   v = pe[((size_t)(b * 1024 + s - 1)) * 768 + d] + loadf(pos, (size_t)s * 768 + d, mode);
    else                 v = 0.f;
    X[idx] = v;
}

extern "C" void kernel_launch(void* const* d_in, const int* in_sizes, int n_in,
                              void* d_out, int out_size, void* d_ws, size_t ws_size,
                              hipStream_t stream)
{
    const void* pixel   = d_in[0];
    const void* patch_w = d_in[1];
    const void* patch_b = d_in[2];
    const void* cls     = d_in[3];
    const void* pos     = d_in[4];
    const void* Wq  = d_in[5];
    const void* bq  = d_in[6];
    const void* Wk  = d_in[7];
    const void* bk  = d_in[8];
    const void* Wv  = d_in[9];
    const void* bv  = d_in[10];
    const void* Wo  = d_in[11];
    const void* bo  = d_in[12];
    const void* ln1g = d_in[13];
    const void* ln1b = d_in[14];
    const void* ln2g = d_in[15];
    const void* ln2b = d_in[16];
    const void* fw1 = d_in[17];
    const void* fb1 = d_in[18];
    const void* fw2 = d_in[19];
    const void* fb2 = d_in[20];
    const void* ng  = d_in[21];
    const void* nb  = d_in[22];
    const int*  ra  = (const int*)d_in[23];

    float* ws = (float*)d_ws;
    const size_t SZ = (size_t)BATCH * SEQP * DIM;   // 1,671,168 floats
    float*    X    = ws;
    float*    XN   = ws + SZ;
    ushort_t* QB   = (ushort_t*)(ws + 2 * SZ);      // bf16 now (half the slot)
    ushort_t* KB   = (ushort_t*)(ws + 3 * SZ);
    ushort_t* VB   = (ushort_t*)(ws + 4 * SZ);
    float*    CTX  = ws + 5 * SZ;
    float*    FFH  = ws + 2 * SZ;     // aliases QB..CTX (4*SZ floats), dead then
    float*    PATCH = ws + SZ;        // aliases XN (pre-layer only)
    float*    POUT  = ws + 2 * SZ;    // aliases QB slot (pre-layer only)
    int*      flag  = (int*)(ws + 6 * SZ);

    const int BIG = 1 << 30;
    dim3 blk(256);

    mode_kernel<<<dim3(1), dim3(64), 0, stream>>>((const unsigned*)ln1g, flag);

    patch_kernel<<<dim3((BATCH * 1024 * 768) / 256), blk, 0, stream>>>(pixel, PATCH, flag);
    gemm_kernel<0,0><<<dim3(12, 32), blk, 0, stream>>>(PATCH, 768, patch_w, 0, 768, patch_b, 0,
                                                       nullptr, POUT, 768, 2048, 768, 768, BIG, BIG, flag);
    assemble_kernel<<<dim3((BATCH * SEQP * 768) / 256), blk, 0, stream>>>(POUT, cls, pos, X, flag);

    for (int i = 0; i < NLAYER; i++) {
        const size_t woE = (size_t)i * 768 * 768;     // element offsets
        const size_t bE  = (size_t)i * 768;
        const size_t w1E = (size_t)i * 768 * 3072;
        const size_t b1E = (size_t)i * 3072;
        ln_kernel<<<dim3(BATCH * SEQP), blk, 0, stream>>>(X, ln1g, ln1b, bE, XN, flag);
        gemm_kernel<0,1><<<dim3(12, 34), blk, 0, stream>>>(XN, 768, Wq, woE, 768, bq, bE,
                                                           nullptr, QB, 768, BATCH * SEQP, 768, 768, BIG, BIG, flag);
        gemm_kernel<0,1><<<dim3(12, 34), blk, 0, stream>>>(XN, 768, Wk, woE, 768, bk, bE,
                                                           nullptr, KB, 768, BATCH * SEQP, 768, 768, BIG, BIG, flag);
        gemm_kernel<0,1><<<dim3(12, 34), blk, 0, stream>>>(XN, 768, Wv, woE, 768, bv, bE,
                                                           nullptr, VB, 768, BATCH * SEQP, 768, 768, BIG, BIG, flag);
        attn_kernel<<<dim3(NBLK, NHEAD, BATCH), blk, 0, stream>>>(QB, KB, VB, ra, CTX);
        gemm_kernel<2,0><<<dim3(12, 34), blk, 0, stream>>>(CTX, 768, Wo, woE, 768, bo, bE,
                                                           X, X, 768, BATCH * SEQP, 768, 768, SEQP, ORIG, flag);
        ln_kernel<<<dim3(BATCH * SEQP), blk, 0, stream>>>(X, ln2g, ln2b, bE, XN, flag);
        gemm_kernel<1,0><<<dim3(48, 34), blk, 0, stream>>>(XN, 768, fw1, w1E, 3072, fb1, b1E,
                                                           nullptr, FFH, 3072, BATCH * SEQP, 3072, 768, BIG, BIG, flag);
        gemm_kernel<2,0><<<dim3(12, 34), blk, 0, stream>>>(FFH, 3072, fw2, w1E, 768, fb2, b1E,
                                                           X, X, 768, BATCH * SEQP, 768, 3072, SEQP, ORIG, flag);
    }
    ln_out_kernel<<<dim3(BATCH * SEQP), blk, 0, stream>>>(X, ng, nb, d_out, flag);
}

// Round 5
// 2993.526 us; speedup vs baseline: 2.6449x; 1.9156x over previous
//
#include <hip/hip_runtime.h>
#include <hip/hip_bf16.h>
#include <math.h>

#define SEQP 1088
#define NBLK 17
#define DIM 768
#define NHEAD 12
#define HDIM 64
#define NLAYER 12
#define BATCH 2
#define ORIG 1025
#define NEGV -10000.0f
#define MROWS (BATCH * SEQP)        // 2176
#define QKVN 2304

typedef __attribute__((ext_vector_type(8))) short short8;
typedef __attribute__((ext_vector_type(4))) float floatx4;
typedef unsigned short ushort_t;

__device__ __forceinline__ short f2bf(float f) {
    unsigned u = __float_as_uint(f);
    u += 0x7fff + ((u >> 16) & 1);   // RNE
    return (short)(u >> 16);
}
__device__ __forceinline__ float bf2f(ushort_t u) {
    return __uint_as_float(((unsigned)u) << 16);
}
__device__ __forceinline__ float loadf(const void* p, size_t i, int mode) {
    return mode ? bf2f(((const ushort_t*)p)[i]) : ((const float*)p)[i];
}
__device__ __forceinline__ void async16(const ushort_t* g, ushort_t* l) {
    __builtin_amdgcn_global_load_lds((const __attribute__((address_space(1))) void*)g,
                                     (__attribute__((address_space(3))) void*)l, 16, 0, 0);
}

__global__ void mode_kernel(const unsigned* __restrict__ ln1g, int* __restrict__ flag) {
    if (threadIdx.x == 0 && blockIdx.x == 0)
        flag[0] = (ln1g[0] == 0x3F803F80u) ? 1 : 0;
}

// ===========================================================================
// NEW FAST PATH
// ===========================================================================

// Transpose+convert weights: in[l][K][N] (mode dtype) -> out[l][roff+N][KO] bf16
__global__ __launch_bounds__(256) void wtrans_kernel(
    const void* __restrict__ in, size_t in_lstride, int K, int N,
    ushort_t* __restrict__ out, size_t out_lstride, int roff, int KO,
    const int* __restrict__ flagp)
{
    const int mode = flagp[0];
    __shared__ ushort_t sm[32][33];
    int l = blockIdx.z;
    int n0 = blockIdx.x * 32, k0 = blockIdx.y * 32;
    int t = threadIdx.x;
    int kk = t >> 5, nn = t & 31;
    size_t ib = (size_t)l * in_lstride;
#pragma unroll
    for (int i = 0; i < 4; i++) {
        int k = k0 + kk + i * 8;
        float v = loadf(in, ib + (size_t)k * N + n0 + nn, mode);
        sm[nn][kk + i * 8] = (ushort_t)f2bf(v);
    }
    __syncthreads();
    int kk2 = t & 31, nn2 = t >> 5;
#pragma unroll
    for (int i = 0; i < 4; i++)
        out[(size_t)l * out_lstride + (size_t)(roff + n0 + nn2 + i * 8) * KO + k0 + kk2]
            = sm[nn2 + i * 8][kk2];
}

// Fused QKV bias -> bf16 [12][2304]
__global__ __launch_bounds__(256) void qkvbias_kernel(
    const void* __restrict__ bq, const void* __restrict__ bk,
    const void* __restrict__ bv, ushort_t* __restrict__ out,
    const int* __restrict__ flagp)
{
    const int mode = flagp[0];
    int l = blockIdx.x;
    for (int j = threadIdx.x; j < QKVN; j += 256) {
        float v = (j < 768) ? loadf(bq, (size_t)l * 768 + j, mode)
                : (j < 1536) ? loadf(bk, (size_t)l * 768 + j - 768, mode)
                             : loadf(bv, (size_t)l * 768 + j - 1536, mode);
        out[(size_t)l * QKVN + j] = (ushort_t)f2bf(v);
    }
}

// ---------------------------------------------------------------------------
// GEMM2: out[M, 128-wide ntile] = A[M][K] bf16 @ Wt[N][K] bf16 + bias.
// m97 structure: global_load_lds width-16 staging, [row][32k] contiguous LDS.
// TM in {64,128}; TN=128; BK=32. M,N divisible by tile; K by 32.
// EPI: 0 none, 1 exact GELU, 2 resid add. OBF: bf16 out. bbf: bias is bf16.
// Row store guard: (m % vmod) < vlim.
// ---------------------------------------------------------------------------
template<int TM, int EPI, int OBF>
__global__ __launch_bounds__(256) void gemm2_kernel(
    const ushort_t* __restrict__ A, int K,
    const ushort_t* __restrict__ Wt,
    const void* __restrict__ bias, size_t boff, int bbf,
    const float* __restrict__ resid,
    void* __restrict__ out, int ldo,
    int vmod, int vlim,
    const int* __restrict__ flagp)
{
    constexpr int FN = (TM == 128) ? 4 : 2;
    __shared__ __align__(16) ushort_t Alds[TM * 32];
    __shared__ __align__(16) ushort_t Blds[128 * 32];

    const int mode = flagp[0];
    const int t = threadIdx.x;
    const int w = t >> 6;
    const int lane = t & 63;
    const int lr = lane & 15;
    const int quad = lane >> 4;
    const int m0 = blockIdx.y * TM;
    const int n0 = blockIdx.x * 128;
    const int m_base = (TM == 128) ? ((w >> 1) * 64) : 0;
    const int n_base = (TM == 128) ? ((w & 1) * 64) : (w * 32);

    floatx4 acc[4][FN];
#pragma unroll
    for (int i = 0; i < 4; i++)
#pragma unroll
        for (int j = 0; j < FN; j++) acc[i][j] = (floatx4){0.f, 0.f, 0.f, 0.f};

    const int srow = lane >> 2;          // 0..15
    const int selem = (lane & 3) * 8;    // bf16 elems within 32-k row

    for (int k0 = 0; k0 < K; k0 += 32) {
        {   // stage A: TM/64 chunks of 16 rows per wave
            constexpr int CA = TM / 64;
#pragma unroll
            for (int j = 0; j < CA; j++) {
                int c = w * CA + j;
                async16(A + (size_t)(m0 + c * 16 + srow) * K + k0 + selem,
                        &Alds[c * 512 + lane * 8]);
            }
            // stage B: 2 chunks per wave
#pragma unroll
            for (int j = 0; j < 2; j++) {
                int c = w * 2 + j;
                async16(Wt + (size_t)(n0 + c * 16 + srow) * K + k0 + selem,
                        &Blds[c * 512 + lane * 8]);
            }
        }
        __syncthreads();
        short8 af[4];
#pragma unroll
        for (int i = 0; i < 4; i++)
            af[i] = *(const short8*)&Alds[(m_base + i * 16 + lr) * 32 + quad * 8];
#pragma unroll
        for (int j = 0; j < FN; j++) {
            short8 bf = *(const short8*)&Blds[(n_base + j * 16 + lr) * 32 + quad * 8];
#pragma unroll
            for (int i = 0; i < 4; i++)
                acc[i][j] = __builtin_amdgcn_mfma_f32_16x16x32_bf16(af[i], bf, acc[i][j], 0, 0, 0);
        }
        __syncthreads();
    }

#pragma unroll
    for (int j = 0; j < FN; j++) {
        int n = n0 + n_base + j * 16 + lr;
        float bv = bbf ? bf2f(((const ushort_t*)bias)[boff + n]) : loadf(bias, boff + n, mode);
#pragma unroll
        for (int i = 0; i < 4; i++) {
#pragma unroll
            for (int r = 0; r < 4; r++) {
                int m = m0 + m_base + i * 16 + quad * 4 + r;
                if ((m % vmod) < vlim) {
                    float v = acc[i][j][r] + bv;
                    if (EPI == 1) v = 0.5f * v * (1.0f + erff(v * 0.70710678118654752f));
                    if (EPI == 2) v += resid[(size_t)m * ldo + n];
                    if (OBF) ((ushort_t*)out)[(size_t)m * ldo + n] = (ushort_t)f2bf(v);
                    else     ((float*)out)[(size_t)m * ldo + n] = v;
                }
            }
        }
    }
}

// LayerNorm f32 X -> bf16 XN (pad rows zeroed)
__global__ __launch_bounds__(256) void ln2_kernel(
    const float* __restrict__ X, const void* __restrict__ g,
    const void* __restrict__ bta, size_t goff, ushort_t* __restrict__ out,
    const int* __restrict__ flagp)
{
    const int mode = flagp[0];
    int r = blockIdx.x;
    int s = r % SEQP;
    int t = threadIdx.x;
    ushort_t* o = out + (size_t)r * DIM;
    if (s >= ORIG) {
        o[t] = 0; o[t + 256] = 0; o[t + 512] = 0;
        return;
    }
    const float* x = X + (size_t)r * DIM;
    float v0 = x[t], v1 = x[t + 256], v2 = x[t + 512];
    float sum = v0 + v1 + v2;
    float sq  = v0 * v0 + v1 * v1 + v2 * v2;
    for (int off = 32; off >= 1; off >>= 1) {
        sum += __shfl_down(sum, off);
        sq  += __shfl_down(sq, off);
    }
    __shared__ float ws_[4], wq_[4], stats[2];
    int wv = t >> 6, ln = t & 63;
    if (ln == 0) { ws_[wv] = sum; wq_[wv] = sq; }
    __syncthreads();
    if (t == 0) {
        float S = ws_[0] + ws_[1] + ws_[2] + ws_[3];
        float Q = wq_[0] + wq_[1] + wq_[2] + wq_[3];
        float mean = S * (1.0f / DIM);
        float var  = Q * (1.0f / DIM) - mean * mean;
        stats[0] = mean; stats[1] = rsqrtf(var + 1e-5f);
    }
    __syncthreads();
    float mean = stats[0], rstd = stats[1];
    o[t]       = (ushort_t)f2bf((v0 - mean) * rstd * loadf(g, goff + t, mode)       + loadf(bta, goff + t, mode));
    o[t + 256] = (ushort_t)f2bf((v1 - mean) * rstd * loadf(g, goff + t + 256, mode) + loadf(bta, goff + t + 256, mode));
    o[t + 512] = (ushort_t)f2bf((v2 - mean) * rstd * loadf(g, goff + t + 512, mode) + loadf(bta, goff + t + 512, mode));
}

// Attention on fused QKV layout [2176][2304] bf16; ctx out bf16 [2176][768].
__global__ __launch_bounds__(256) void attn2_kernel(
    const ushort_t* __restrict__ qkv, const int* __restrict__ rand_attn,
    ushort_t* __restrict__ ctx)
{
    __shared__ __align__(16) ushort_t Ks[64][72];
    __shared__ __align__(16) ushort_t VT[64][72];
    __shared__ __align__(16) ushort_t Ps[4][16][72];

    const int qi = blockIdx.x;
    const int h  = blockIdx.y;
    const int b  = blockIdx.z;
    const int t  = threadIdx.x;
    const int w    = t >> 6;
    const int lane = t & 63;
    const int lr   = lane & 15;
    const int quad = lane >> 4;

    int list[NBLK];
    int nk;
    if (qi == 0 || qi == NBLK - 1) {
        nk = NBLK;
        for (int i = 0; i < NBLK; i++) list[i] = i;
    } else {
        const int* ra = rand_attn + (h * (NBLK - 2) + (qi - 1)) * 3;
        if (qi == 1)           { list[0]=0; list[1]=1;  list[2]=2;  list[3]=16; nk=4; }
        else if (qi == NBLK-2) { list[0]=0; list[1]=14; list[2]=15; list[3]=16; nk=4; }
        else { list[0]=0; list[1]=qi-1; list[2]=qi; list[3]=qi+1; list[4]=16; nk=5; }
        list[nk++] = ra[0]; list[nk++] = ra[1]; list[nk++] = ra[2];
    }

    const ushort_t* qp = qkv + (size_t)(b * SEQP + qi * 64 + w * 16 + lr) * QKVN + h * HDIM + quad * 8;
    short8 aq0 = *(const short8*)qp;
    short8 aq1 = *(const short8*)(qp + 32);

    floatx4 O[4];
#pragma unroll
    for (int i = 0; i < 4; i++) O[i] = (floatx4){0.f, 0.f, 0.f, 0.f};
    float m_[4], l_[4];
#pragma unroll
    for (int r = 0; r < 4; r++) { m_[r] = -1e30f; l_[r] = 0.f; }

    const int k_row = t >> 2, k_dg = (t & 3) * 16;
    const int v_d   = t & 63, v_r0 = (t >> 6) * 16;

    for (int ib = 0; ib < nk; ib++) {
        const int kb = list[ib];
        __syncthreads();
        {   // stage K [krow][d]
            const ushort_t* kp = qkv + (size_t)(b * SEQP + kb * 64 + k_row) * QKVN + 768 + h * HDIM + k_dg;
            *(short8*)&Ks[k_row][k_dg]     = *(const short8*)kp;
            *(short8*)&Ks[k_row][k_dg + 8] = *(const short8*)(kp + 8);
        }
        {   // stage V transposed [d][vrow]
            const ushort_t* vp = qkv + (size_t)(b * SEQP + kb * 64 + v_r0) * QKVN + 1536 + h * HDIM + v_d;
            ushort_t tmp[16];
#pragma unroll
            for (int r = 0; r < 16; r++) tmp[r] = vp[(size_t)r * QKVN];
#pragma unroll
            for (int i = 0; i < 8; i++) {
                unsigned pk = (unsigned)tmp[2 * i] | ((unsigned)tmp[2 * i + 1] << 16);
                *(unsigned*)&VT[v_d][v_r0 + 2 * i] = pk;
            }
        }
        __syncthreads();

        float s[4][4];
#pragma unroll
        for (int kt = 0; kt < 4; kt++) {
            short8 b0 = *(const short8*)&Ks[kt * 16 + lr][quad * 8];
            short8 b1 = *(const short8*)&Ks[kt * 16 + lr][32 + quad * 8];
            floatx4 z = (floatx4){0.f, 0.f, 0.f, 0.f};
            z = __builtin_amdgcn_mfma_f32_16x16x32_bf16(aq0, b0, z, 0, 0, 0);
            z = __builtin_amdgcn_mfma_f32_16x16x32_bf16(aq1, b1, z, 0, 0, 0);
            float madd = (kb * 64 + kt * 16 + lr >= ORIG) ? NEGV : 0.f;
#pragma unroll
            for (int r = 0; r < 4; r++) s[kt][r] = z[r] * 0.125f + madd;
        }
        float rmax[4];
#pragma unroll
        for (int r = 0; r < 4; r++)
            rmax[r] = fmaxf(fmaxf(s[0][r], s[1][r]), fmaxf(s[2][r], s[3][r]));
#pragma unroll
        for (int d = 1; d < 16; d <<= 1)
#pragma unroll
            for (int r = 0; r < 4; r++) rmax[r] = fmaxf(rmax[r], __shfl_xor(rmax[r], d));
        float alpha[4];
#pragma unroll
        for (int r = 0; r < 4; r++) {
            float mnew = fmaxf(m_[r], rmax[r]);
            alpha[r] = __expf(m_[r] - mnew);
            m_[r] = mnew;
        }
        float rsum[4];
#pragma unroll
        for (int r = 0; r < 4; r++) rsum[r] = 0.f;
#pragma unroll
        for (int kt = 0; kt < 4; kt++)
#pragma unroll
            for (int r = 0; r < 4; r++) {
                float pv = __expf(s[kt][r] - m_[r]);
                s[kt][r] = pv;
                rsum[r] += pv;
            }
#pragma unroll
        for (int d = 1; d < 16; d <<= 1)
#pragma unroll
            for (int r = 0; r < 4; r++) rsum[r] += __shfl_xor(rsum[r], d);
#pragma unroll
        for (int r = 0; r < 4; r++) l_[r] = l_[r] * alpha[r] + rsum[r];

#pragma unroll
        for (int kt = 0; kt < 4; kt++)
#pragma unroll
            for (int r = 0; r < 4; r++)
                Ps[w][quad * 4 + r][kt * 16 + lr] = (ushort_t)f2bf(s[kt][r]);
#pragma unroll
        for (int nt = 0; nt < 4; nt++)
#pragma unroll
            for (int r = 0; r < 4; r++) O[nt][r] *= alpha[r];

        short8 pa0 = *(const short8*)&Ps[w][lr][quad * 8];
        short8 pa1 = *(const short8*)&Ps[w][lr][32 + quad * 8];
#pragma unroll
        for (int nt = 0; nt < 4; nt++) {
            short8 v0 = *(const short8*)&VT[nt * 16 + lr][quad * 8];
            short8 v1 = *(const short8*)&VT[nt * 16 + lr][32 + quad * 8];
            O[nt] = __builtin_amdgcn_mfma_f32_16x16x32_bf16(pa0, v0, O[nt], 0, 0, 0);
            O[nt] = __builtin_amdgcn_mfma_f32_16x16x32_bf16(pa1, v1, O[nt], 0, 0, 0);
        }
    }

#pragma unroll
    for (int r = 0; r < 4; r++) {
        float inv = 1.0f / l_[r];
        ushort_t* op = ctx + (size_t)(b * SEQP + qi * 64 + w * 16 + quad * 4 + r) * DIM + h * HDIM + lr;
#pragma unroll
        for (int nt = 0; nt < 4; nt++) op[nt * 16] = (ushort_t)f2bf(O[nt][r] * inv);
    }
}

// patch extraction -> bf16
__global__ __launch_bounds__(256) void patch2_kernel(
    const void* __restrict__ px, ushort_t* __restrict__ patches,
    const int* __restrict__ flagp)
{
    const int mode = flagp[0];
    int idx = blockIdx.x * 256 + threadIdx.x;
    int f = idx % 768;
    int rest = idx / 768;
    int p = rest % 1024;
    int b = rest / 1024;
    int gy = p >> 5, gx = p & 31;
    int c = f >> 8, rr = f & 255;
    int py = rr >> 4, pxl = rr & 15;
    patches[idx] = (ushort_t)f2bf(loadf(px, (((size_t)(b * 3 + c) * 512) + gy * 16 + py) * 512 + gx * 16 + pxl, mode));
}

// X f32 from bf16 patch-embed out + cls/pos
__global__ __launch_bounds__(256) void assemble2_kernel(
    const ushort_t* __restrict__ pe, const void* __restrict__ cls,
    const void* __restrict__ pos, float* __restrict__ X,
    const int* __restrict__ flagp)
{
    const int mode = flagp[0];
    int idx = blockIdx.x * 256 + threadIdx.x;
    int d = idx % 768;
    int rest = idx / 768;
    int s = rest % SEQP;
    int b = rest / SEQP;
    float v;
    if (s == 0)          v = loadf(cls, d, mode) + loadf(pos, d, mode);
    else if (s < ORIG)   v = bf2f(pe[((size_t)(b * 1024 + s - 1)) * 768 + d]) + loadf(pos, (size_t)s * 768 + d, mode);
    else                 v = 0.f;
    X[idx] = v;
}

// Final LN -> output (dtype per mode), compact (B, ORIG, D)
__global__ __launch_bounds__(256) void ln_out_kernel(
    const float* __restrict__ X, const void* __restrict__ g,
    const void* __restrict__ bta, void* __restrict__ out,
    const int* __restrict__ flagp)
{
    const int mode = flagp[0];
    int r = blockIdx.x;
    int b = r / SEQP, s = r % SEQP;
    if (s >= ORIG) return;
    int t = threadIdx.x;
    const float* x = X + (size_t)r * DIM;
    float v0 = x[t], v1 = x[t + 256], v2 = x[t + 512];
    float sum = v0 + v1 + v2;
    float sq  = v0 * v0 + v1 * v1 + v2 * v2;
    for (int off = 32; off >= 1; off >>= 1) {
        sum += __shfl_down(sum, off);
        sq  += __shfl_down(sq, off);
    }
    __shared__ float ws_[4], wq_[4], stats[2];
    int wv = t >> 6, ln = t & 63;
    if (ln == 0) { ws_[wv] = sum; wq_[wv] = sq; }
    __syncthreads();
    if (t == 0) {
        float S = ws_[0] + ws_[1] + ws_[2] + ws_[3];
        float Q = wq_[0] + wq_[1] + wq_[2] + wq_[3];
        float mean = S * (1.0f / DIM);
        float var  = Q * (1.0f / DIM) - mean * mean;
        stats[0] = mean; stats[1] = rsqrtf(var + 1e-5f);
    }
    __syncthreads();
    float mean = stats[0], rstd = stats[1];
    size_t base = ((size_t)b * ORIG + s) * DIM;
    float r0 = (v0 - mean) * rstd * loadf(g, t, mode)       + loadf(bta, t, mode);
    float r1 = (v1 - mean) * rstd * loadf(g, t + 256, mode) + loadf(bta, t + 256, mode);
    float r2 = (v2 - mean) * rstd * loadf(g, t + 512, mode) + loadf(bta, t + 512, mode);
    if (mode) {
        ushort_t* o = (ushort_t*)out + base;
        o[t] = (ushort_t)f2bf(r0); o[t + 256] = (ushort_t)f2bf(r1); o[t + 512] = (ushort_t)f2bf(r2);
    } else {
        float* o = (float*)out + base;
        o[t] = r0; o[t + 256] = r1; o[t + 512] = r2;
    }
}

// ===========================================================================
// FALLBACK PATH (round-4, used only if ws_size is too small for weight prep)
// ===========================================================================
template<int EPI, int OBF>
__global__ __launch_bounds__(256) void gemm_kernel(
    const float* __restrict__ A, int lda,
    const void* __restrict__ W, size_t woff, int ldw,
    const void* __restrict__ bias, size_t boff,
    const float* __restrict__ resid,
    void* __restrict__ out, int ldo,
    int M, int N, int K, int vmod, int vlim,
    const int* __restrict__ flagp)
{
    __shared__ __align__(16) short As[2][64][40];
    __shared__ __align__(16) short Bs[2][64][40];
    const int mode = flagp[0];
    const int t = threadIdx.x;
    const int wave = t >> 6, lane = t & 63, lr = lane & 15, quad = lane >> 4;
    const int m0 = blockIdx.y * 64, n0 = blockIdx.x * 64;
    floatx4 acc[4];
#pragma unroll
    for (int i = 0; i < 4; i++) acc[i] = (floatx4){0.f, 0.f, 0.f, 0.f};
    const int a_row = t >> 2, a_kg = t & 3, a_sw = (a_row >> 3) & 3;
    const int b_n = t & 63, b_kg = t >> 6, b_sw = (b_n >> 3) & 3;
    const int fa_row = wave * 16 + lr, fa_sw = (fa_row >> 3) & 3;
    for (int k0 = 0; k0 < K; k0 += 32) {
        {
            int gm = m0 + a_row;
            floatx4 v0, v1;
            if (gm < M) {
                const float* p = A + (size_t)gm * lda + k0 + a_kg * 8;
                v0 = *(const floatx4*)p; v1 = *(const floatx4*)(p + 4);
            } else { v0 = (floatx4){0.f,0.f,0.f,0.f}; v1 = v0; }
            short8 hi, lo;
#pragma unroll
            for (int e = 0; e < 4; e++) {
                short h0 = f2bf(v0[e]); hi[e] = h0; lo[e] = f2bf(v0[e] - bf2f((ushort_t)h0));
                short h1 = f2bf(v1[e]); hi[e+4] = h1; lo[e+4] = f2bf(v1[e] - bf2f((ushort_t)h1));
            }
            int col = (a_kg ^ a_sw) * 8;
            *(short8*)&As[0][a_row][col] = hi; *(short8*)&As[1][a_row][col] = lo;
        }
        {
            short8 hi, lo;
            size_t off = woff + (size_t)(k0 + b_kg * 8) * ldw + n0 + b_n;
            if (mode) {
                const ushort_t* p = (const ushort_t*)W + off;
#pragma unroll
                for (int j = 0; j < 8; j++) { hi[j] = (short)p[(size_t)j * ldw]; lo[j] = 0; }
            } else {
                const float* p = (const float*)W + off;
#pragma unroll
                for (int j = 0; j < 8; j++) {
                    float v = p[(size_t)j * ldw];
                    short h = f2bf(v); hi[j] = h; lo[j] = f2bf(v - bf2f((ushort_t)h));
                }
            }
            int col = (b_kg ^ b_sw) * 8;
            *(short8*)&Bs[0][b_n][col] = hi; *(short8*)&Bs[1][b_n][col] = lo;
        }
        __syncthreads();
        int acol = (quad ^ fa_sw) * 8;
        short8 ah = *(const short8*)&As[0][fa_row][acol];
        short8 al = *(const short8*)&As[1][fa_row][acol];
#pragma unroll
        for (int nt = 0; nt < 4; nt++) {
            int n = nt * 16 + lr;
            int bcol = (quad ^ ((n >> 3) & 3)) * 8;
            short8 bh = *(const short8*)&Bs[0][n][bcol];
            short8 bl = *(const short8*)&Bs[1][n][bcol];
            acc[nt] = __builtin_amdgcn_mfma_f32_16x16x32_bf16(al, bh, acc[nt], 0, 0, 0);
            acc[nt] = __builtin_amdgcn_mfma_f32_16x16x32_bf16(ah, bl, acc[nt], 0, 0, 0);
            acc[nt] = __builtin_amdgcn_mfma_f32_16x16x32_bf16(ah, bh, acc[nt], 0, 0, 0);
        }
        __syncthreads();
    }
#pragma unroll
    for (int nt = 0; nt < 4; nt++) {
        int n = n0 + nt * 16 + lr;
        float bv = loadf(bias, boff + n, mode);
#pragma unroll
        for (int r = 0; r < 4; r++) {
            int m = m0 + wave * 16 + quad * 4 + r;
            if (m < M && (m % vmod) < vlim) {
                float v = acc[nt][r] + bv;
                if (EPI == 1) v = 0.5f * v * (1.0f + erff(v * 0.70710678118654752f));
                if (EPI == 2) v += resid[(size_t)m * ldo + n];
                if (OBF) ((ushort_t*)out)[(size_t)m * ldo + n] = (ushort_t)f2bf(v);
                else     ((float*)out)[(size_t)m * ldo + n] = v;
            }
        }
    }
}

__global__ __launch_bounds__(256) void ln_kernel(
    const float* __restrict__ X, const void* __restrict__ g,
    const void* __restrict__ bta, size_t goff, float* __restrict__ out,
    const int* __restrict__ flagp)
{
    const int mode = flagp[0];
    int r = blockIdx.x;
    int s = r % SEQP;
    int t = threadIdx.x;
    float* o = out + (size_t)r * DIM;
    if (s >= ORIG) { o[t] = 0.f; o[t + 256] = 0.f; o[t + 512] = 0.f; return; }
    const float* x = X + (size_t)r * DIM;
    float v0 = x[t], v1 = x[t + 256], v2 = x[t + 512];
    float sum = v0 + v1 + v2;
    float sq  = v0 * v0 + v1 * v1 + v2 * v2;
    for (int off = 32; off >= 1; off >>= 1) { sum += __shfl_down(sum, off); sq += __shfl_down(sq, off); }
    __shared__ float ws_[4], wq_[4], stats[2];
    int wv = t >> 6, ln = t & 63;
    if (ln == 0) { ws_[wv] = sum; wq_[wv] = sq; }
    __syncthreads();
    if (t == 0) {
        float S = ws_[0] + ws_[1] + ws_[2] + ws_[3];
        float Q = wq_[0] + wq_[1] + wq_[2] + wq_[3];
        float mean = S * (1.0f / DIM);
        float var  = Q * (1.0f / DIM) - mean * mean;
        stats[0] = mean; stats[1] = rsqrtf(var + 1e-5f);
    }
    __syncthreads();
    float mean = stats[0], rstd = stats[1];
    o[t]       = (v0 - mean) * rstd * loadf(g, goff + t, mode)       + loadf(bta, goff + t, mode);
    o[t + 256] = (v1 - mean) * rstd * loadf(g, goff + t + 256, mode) + loadf(bta, goff + t + 256, mode);
    o[t + 512] = (v2 - mean) * rstd * loadf(g, goff + t + 512, mode) + loadf(bta, goff + t + 512, mode);
}

__global__ __launch_bounds__(256) void attn_kernel(
    const ushort_t* __restrict__ qm, const ushort_t* __restrict__ km,
    const ushort_t* __restrict__ vm, const int* __restrict__ rand_attn,
    float* __restrict__ ctx)
{
    __shared__ __align__(16) ushort_t Ks[64][72];
    __shared__ __align__(16) ushort_t VT[64][72];
    __shared__ __align__(16) ushort_t Ps[4][16][72];
    const int qi = blockIdx.x, h = blockIdx.y, b = blockIdx.z;
    const int t = threadIdx.x, w = t >> 6, lane = t & 63, lr = lane & 15, quad = lane >> 4;
    int list[NBLK]; int nk;
    if (qi == 0 || qi == NBLK - 1) { nk = NBLK; for (int i = 0; i < NBLK; i++) list[i] = i; }
    else {
        const int* ra = rand_attn + (h * (NBLK - 2) + (qi - 1)) * 3;
        if (qi == 1)           { list[0]=0; list[1]=1;  list[2]=2;  list[3]=16; nk=4; }
        else if (qi == NBLK-2) { list[0]=0; list[1]=14; list[2]=15; list[3]=16; nk=4; }
        else { list[0]=0; list[1]=qi-1; list[2]=qi; list[3]=qi+1; list[4]=16; nk=5; }
        list[nk++] = ra[0]; list[nk++] = ra[1]; list[nk++] = ra[2];
    }
    const ushort_t* qp = qm + ((size_t)(b * SEQP + qi * 64 + w * 16 + lr)) * DIM + h * HDIM + quad * 8;
    short8 aq0 = *(const short8*)qp;
    short8 aq1 = *(const short8*)(qp + 32);
    floatx4 O[4];
#pragma unroll
    for (int i = 0; i < 4; i++) O[i] = (floatx4){0.f, 0.f, 0.f, 0.f};
    float m_[4], l_[4];
#pragma unroll
    for (int r = 0; r < 4; r++) { m_[r] = -1e30f; l_[r] = 0.f; }
    const int k_row = t >> 2, k_dg = (t & 3) * 16;
    const int v_d = t & 63, v_r0 = (t >> 6) * 16;
    for (int ib = 0; ib < nk; ib++) {
        const int kb = list[ib];
        __syncthreads();
        {
            const ushort_t* kp = km + ((size_t)(b * SEQP + kb * 64 + k_row)) * DIM + h * HDIM + k_dg;
            *(short8*)&Ks[k_row][k_dg]     = *(const short8*)kp;
            *(short8*)&Ks[k_row][k_dg + 8] = *(const short8*)(kp + 8);
        }
        {
            const ushort_t* vp = vm + ((size_t)(b * SEQP + kb * 64 + v_r0)) * DIM + h * HDIM + v_d;
            ushort_t tmp[16];
#pragma unroll
            for (int r = 0; r < 16; r++) tmp[r] = vp[(size_t)r * DIM];
#pragma unroll
            for (int i = 0; i < 8; i++) {
                unsigned pk = (unsigned)tmp[2 * i] | ((unsigned)tmp[2 * i + 1] << 16);
                *(unsigned*)&VT[v_d][v_r0 + 2 * i] = pk;
            }
        }
        __syncthreads();
        float s[4][4];
#pragma unroll
        for (int kt = 0; kt < 4; kt++) {
            short8 b0 = *(const short8*)&Ks[kt * 16 + lr][quad * 8];
            short8 b1 = *(const short8*)&Ks[kt * 16 + lr][32 + quad * 8];
            floatx4 z = (floatx4){0.f, 0.f, 0.f, 0.f};
            z = __builtin_amdgcn_mfma_f32_16x16x32_bf16(aq0, b0, z, 0, 0, 0);
            z = __builtin_amdgcn_mfma_f32_16x16x32_bf16(aq1, b1, z, 0, 0, 0);
            float madd = (kb * 64 + kt * 16 + lr >= ORIG) ? NEGV : 0.f;
#pragma unroll
            for (int r = 0; r < 4; r++) s[kt][r] = z[r] * 0.125f + madd;
        }
        float rmax[4];
#pragma unroll
        for (int r = 0; r < 4; r++) rmax[r] = fmaxf(fmaxf(s[0][r], s[1][r]), fmaxf(s[2][r], s[3][r]));
#pragma unroll
        for (int d = 1; d < 16; d <<= 1)
#pragma unroll
            for (int r = 0; r < 4; r++) rmax[r] = fmaxf(rmax[r], __shfl_xor(rmax[r], d));
        float alpha[4];
#pragma unroll
        for (int r = 0; r < 4; r++) {
            float mnew = fmaxf(m_[r], rmax[r]);
            alpha[r] = __expf(m_[r] - mnew);
            m_[r] = mnew;
        }
        float rsum[4];
#pragma unroll
        for (int r = 0; r < 4; r++) rsum[r] = 0.f;
#pragma unroll
        for (int kt = 0; kt < 4; kt++)
#pragma unroll
            for (int r = 0; r < 4; r++) {
                float pv = __expf(s[kt][r] - m_[r]);
                s[kt][r] = pv; rsum[r] += pv;
            }
#pragma unroll
        for (int d = 1; d < 16; d <<= 1)
#pragma unroll
            for (int r = 0; r < 4; r++) rsum[r] += __shfl_xor(rsum[r], d);
#pragma unroll
        for (int r = 0; r < 4; r++) l_[r] = l_[r] * alpha[r] + rsum[r];
#pragma unroll
        for (int kt = 0; kt < 4; kt++)
#pragma unroll
            for (int r = 0; r < 4; r++)
                Ps[w][quad * 4 + r][kt * 16 + lr] = (ushort_t)f2bf(s[kt][r]);
#pragma unroll
        for (int nt = 0; nt < 4; nt++)
#pragma unroll
            for (int r = 0; r < 4; r++) O[nt][r] *= alpha[r];
        short8 pa0 = *(const short8*)&Ps[w][lr][quad * 8];
        short8 pa1 = *(const short8*)&Ps[w][lr][32 + quad * 8];
#pragma unroll
        for (int nt = 0; nt < 4; nt++) {
            short8 v0 = *(const short8*)&VT[nt * 16 + lr][quad * 8];
            short8 v1 = *(const short8*)&VT[nt * 16 + lr][32 + quad * 8];
            O[nt] = __builtin_amdgcn_mfma_f32_16x16x32_bf16(pa0, v0, O[nt], 0, 0, 0);
            O[nt] = __builtin_amdgcn_mfma_f32_16x16x32_bf16(pa1, v1, O[nt], 0, 0, 0);
        }
    }
#pragma unroll
    for (int r = 0; r < 4; r++) {
        float inv = 1.0f / l_[r];
        float* op = ctx + ((size_t)(b * SEQP + qi * 64 + w * 16 + quad * 4 + r)) * DIM + h * HDIM + lr;
#pragma unroll
        for (int nt = 0; nt < 4; nt++) op[nt * 16] = O[nt][r] * inv;
    }
}

__global__ __launch_bounds__(256) void patch_kernel(
    const void* __restrict__ px, float* __restrict__ patches,
    const int* __restrict__ flagp)
{
    const int mode = flagp[0];
    int idx = blockIdx.x * 256 + threadIdx.x;
    int f = idx % 768;
    int rest = idx / 768;
    int p = rest % 1024;
    int b = rest / 1024;
    int gy = p >> 5, gx = p & 31;
    int c = f >> 8, rr = f & 255;
    int py = rr >> 4, pxl = rr & 15;
    patches[idx] = loadf(px, (((size_t)(b * 3 + c) * 512) + gy * 16 + py) * 512 + gx * 16 + pxl, mode);
}

__global__ __launch_bounds__(256) void assemble_kernel(
    const float* __restrict__ pe, const void* __restrict__ cls,
    const void* __restrict__ pos, float* __restrict__ X,
    const int* __restrict__ flagp)
{
    const int mode = flagp[0];
    int idx = blockIdx.x * 256 + threadIdx.x;
    int d = idx % 768;
    int rest = idx / 768;
    int s = rest % SEQP;
    int b = rest / SEQP;
    float v;
    if (s == 0)          v = loadf(cls, d, mode) + loadf(pos, d, mode);
    else if (s < ORIG)   v = pe[((size_t)(b * 1024 + s - 1)) * 768 + d] + loadf(pos, (size_t)s * 768 + d, mode);
    else                 v = 0.f;
    X[idx] = v;
}

// ===========================================================================
extern "C" void kernel_launch(void* const* d_in, const int* in_sizes, int n_in,
                              void* d_out, int out_size, void* d_ws, size_t ws_size,
                              hipStream_t stream)
{
    const void* pixel   = d_in[0];
    const void* patch_w = d_in[1];
    const void* patch_b = d_in[2];
    const void* cls     = d_in[3];
    const void* pos     = d_in[4];
    const void* Wq  = d_in[5];
    const void* bq  = d_in[6];
    const void* Wk  = d_in[7];
    const void* bk  = d_in[8];
    const void* Wv  = d_in[9];
    const void* bv  = d_in[10];
    const void* Wo  = d_in[11];
    const void* bo  = d_in[12];
    const void* ln1g = d_in[13];
    const void* ln1b = d_in[14];
    const void* ln2g = d_in[15];
    const void* ln2b = d_in[16];
    const void* fw1 = d_in[17];
    const void* fb1 = d_in[18];
    const void* fw2 = d_in[19];
    const void* fb2 = d_in[20];
    const void* ng  = d_in[21];
    const void* nb  = d_in[22];
    const int*  ra  = (const int*)d_in[23];

    char* wsB = (char*)d_ws;
    dim3 blk(256);
    const int BIG = 1 << 30;

    // new-path workspace layout (bytes)
    const size_t oX    = 0;                       // f32  [2176][768]
    const size_t oXN   = 6684672;                 // bf16 [2176][768]
    const size_t oQKV  = 10027008;                // bf16 [2176][2304]
    const size_t oCTX  = 20054016;                // bf16 [2176][768]   (alias POUT)
    const size_t oFFH  = 23396352;                // bf16 [2176][3072]  (alias PATCH)
    const size_t oFLAG = 36765696;
    const size_t oQKVt = 36766208;                // bf16 [12][2304][768]
    const size_t oWot  = 79233536;                // bf16 [12][768][768]
    const size_t oW1t  = 93389312;                // bf16 [12][3072][768]
    const size_t oW2t  = 150012416;               // bf16 [12][768][3072]
    const size_t oPWt  = 206635520;               // bf16 [768][768]
    const size_t oQKVb = 207815168;               // bf16 [12][2304]
    const size_t NEED  = 207870464;

    if (ws_size >= NEED) {
        // -------- fast path --------
        float*    X    = (float*)(wsB + oX);
        ushort_t* XN   = (ushort_t*)(wsB + oXN);
        ushort_t* QKV  = (ushort_t*)(wsB + oQKV);
        ushort_t* CTX  = (ushort_t*)(wsB + oCTX);
        ushort_t* FFH  = (ushort_t*)(wsB + oFFH);
        int*      flag = (int*)(wsB + oFLAG);
        ushort_t* QKVt = (ushort_t*)(wsB + oQKVt);
        ushort_t* Wot  = (ushort_t*)(wsB + oWot);
        ushort_t* W1t  = (ushort_t*)(wsB + oW1t);
        ushort_t* W2t  = (ushort_t*)(wsB + oW2t);
        ushort_t* PWt  = (ushort_t*)(wsB + oPWt);
        ushort_t* QKVb = (ushort_t*)(wsB + oQKVb);
        ushort_t* PATCH = FFH;
        ushort_t* POUT  = CTX;

        mode_kernel<<<dim3(1), dim3(64), 0, stream>>>((const unsigned*)ln1g, flag);

        // weight prep (independent of activations)
        wtrans_kernel<<<dim3(24, 24, 12), blk, 0, stream>>>(Wq, 589824, 768, 768, QKVt, 1769472, 0,    768, flag);
        wtrans_kernel<<<dim3(24, 24, 12), blk, 0, stream>>>(Wk, 589824, 768, 768, QKVt, 1769472, 768,  768, flag);
        wtrans_kernel<<<dim3(24, 24, 12), blk, 0, stream>>>(Wv, 589824, 768, 768, QKVt, 1769472, 1536, 768, flag);
        wtrans_kernel<<<dim3(24, 24, 12), blk, 0, stream>>>(Wo, 589824, 768, 768, Wot,  589824,  0,    768, flag);
        wtrans_kernel<<<dim3(96, 24, 12), blk, 0, stream>>>(fw1, 2359296, 768, 3072, W1t, 2359296, 0, 768, flag);
        wtrans_kernel<<<dim3(24, 96, 12), blk, 0, stream>>>(fw2, 2359296, 3072, 768, W2t, 2359296, 0, 3072, flag);
        wtrans_kernel<<<dim3(24, 24, 1),  blk, 0, stream>>>(patch_w, 0, 768, 768, PWt, 0, 0, 768, flag);
        qkvbias_kernel<<<dim3(12), blk, 0, stream>>>(bq, bk, bv, QKVb, flag);

        // embedding
        patch2_kernel<<<dim3((BATCH * 1024 * 768) / 256), blk, 0, stream>>>(pixel, PATCH, flag);
        gemm2_kernel<128,0,1><<<dim3(6, 16), blk, 0, stream>>>(PATCH, 768, PWt, patch_b, 0, 0,
                                                               nullptr, POUT, 768, BIG, BIG, flag);
        assemble2_kernel<<<dim3((BATCH * SEQP * 768) / 256), blk, 0, stream>>>(POUT, cls, pos, X, flag);

        for (int i = 0; i < NLAYER; i++) {
            const size_t bE  = (size_t)i * 768;
            const size_t b1E = (size_t)i * 3072;
            ln2_kernel<<<dim3(MROWS), blk, 0, stream>>>(X, ln1g, ln1b, bE, XN, flag);
            gemm2_kernel<128,0,1><<<dim3(18, 17), blk, 0, stream>>>(XN, 768, QKVt + (size_t)i * 1769472,
                                                                    QKVb, (size_t)i * QKVN, 1,
                                                                    nullptr, QKV, QKVN, BIG, BIG, flag);
            attn2_kernel<<<dim3(NBLK, NHEAD, BATCH), blk, 0, stream>>>(QKV, ra, CTX);
            gemm2_kernel<64,2,0><<<dim3(6, 34), blk, 0, stream>>>(CTX, 768, Wot + (size_t)i * 589824,
                                                                  bo, bE, 0, X, X, 768, SEQP, ORIG, flag);
            ln2_kernel<<<dim3(MROWS), blk, 0, stream>>>(X, ln2g, ln2b, bE, XN, flag);
            gemm2_kernel<128,1,1><<<dim3(24, 17), blk, 0, stream>>>(XN, 768, W1t + (size_t)i * 2359296,
                                                                    fb1, b1E, 0, nullptr, FFH, 3072, BIG, BIG, flag);
            gemm2_kernel<64,2,0><<<dim3(6, 34), blk, 0, stream>>>(FFH, 3072, W2t + (size_t)i * 2359296,
                                                                  fb2, bE, 0, X, X, 768, SEQP, ORIG, flag);
        }
        ln_out_kernel<<<dim3(MROWS), blk, 0, stream>>>(X, ng, nb, d_out, flag);
    } else {
        // -------- fallback: round-4 path --------
        float* ws = (float*)d_ws;
        const size_t SZ = (size_t)BATCH * SEQP * DIM;
        float*    X    = ws;
        float*    XN   = ws + SZ;
        ushort_t* QB   = (ushort_t*)(ws + 2 * SZ);
        ushort_t* KB   = (ushort_t*)(ws + 3 * SZ);
        ushort_t* VB   = (ushort_t*)(ws + 4 * SZ);
        float*    CTX  = ws + 5 * SZ;
        float*    FFH  = ws + 2 * SZ;
        float*    PATCH = ws + SZ;
        float*    POUT  = ws + 2 * SZ;
        int*      flag  = (int*)(ws + 6 * SZ);

        mode_kernel<<<dim3(1), dim3(64), 0, stream>>>((const unsigned*)ln1g, flag);
        patch_kernel<<<dim3((BATCH * 1024 * 768) / 256), blk, 0, stream>>>(pixel, PATCH, flag);
        gemm_kernel<0,0><<<dim3(12, 32), blk, 0, stream>>>(PATCH, 768, patch_w, 0, 768, patch_b, 0,
                                                           nullptr, POUT, 768, 2048, 768, 768, BIG, BIG, flag);
        assemble_kernel<<<dim3((BATCH * SEQP * 768) / 256), blk, 0, stream>>>(POUT, cls, pos, X, flag);
        for (int i = 0; i < NLAYER; i++) {
            const size_t woE = (size_t)i * 768 * 768;
            const size_t bE  = (size_t)i * 768;
            const size_t w1E = (size_t)i * 768 * 3072;
            const size_t b1E = (size_t)i * 3072;
            ln_kernel<<<dim3(MROWS), blk, 0, stream>>>(X, ln1g, ln1b, bE, XN, flag);
            gemm_kernel<0,1><<<dim3(12, 34), blk, 0, stream>>>(XN, 768, Wq, woE, 768, bq, bE,
                                                               nullptr, QB, 768, MROWS, 768, 768, BIG, BIG, flag);
            gemm_kernel<0,1><<<dim3(12, 34), blk, 0, stream>>>(XN, 768, Wk, woE, 768, bk, bE,
                                                               nullptr, KB, 768, MROWS, 768, 768, BIG, BIG, flag);
            gemm_kernel<0,1><<<dim3(12, 34), blk, 0, stream>>>(XN, 768, Wv, woE, 768, bv, bE,
                                                               nullptr, VB, 768, MROWS, 768, 768, BIG, BIG, flag);
            attn_kernel<<<dim3(NBLK, NHEAD, BATCH), blk, 0, stream>>>(QB, KB, VB, ra, CTX);
            gemm_kernel<2,0><<<dim3(12, 34), blk, 0, stream>>>(CTX, 768, Wo, woE, 768, bo, bE,
                                                               X, X, 768, MROWS, 768, 768, SEQP, ORIG, flag);
            ln_kernel<<<dim3(MROWS), blk, 0, stream>>>(X, ln2g, ln2b, bE, XN, flag);
            gemm_kernel<1,0><<<dim3(48, 34), blk, 0, stream>>>(XN, 768, fw1, w1E, 3072, fb1, b1E,
                                                               nullptr, FFH, 3072, MROWS, 3072, 768, BIG, BIG, flag);
            gemm_kernel<2,0><<<dim3(12, 34), blk, 0, stream>>>(FFH, 3072, fw2, w1E, 768, fb2, b1E,
                                                               X, X, 768, MROWS, 768, 3072, SEQP, ORIG, flag);
        }
        ln_out_kernel<<<dim3(MROWS), blk, 0, stream>>>(X, ng, nb, d_out, flag);
    }
}